// Round 1
// baseline (368.254 us; speedup 1.0000x reference)
//
#include <hip/hip_runtime.h>
#include <hip/hip_bf16.h>

typedef unsigned short u16;
typedef __attribute__((ext_vector_type(8))) short short8;
typedef __attribute__((ext_vector_type(4))) float f32x4;
typedef __attribute__((ext_vector_type(4))) unsigned short u16x4;

#define MFMA16(a, b, c) __builtin_amdgcn_mfma_f32_16x16x32_bf16((a), (b), (c), 0, 0, 0)

__device__ __forceinline__ u16 f2bf(float f) {
  union { float f; unsigned int u; } x; x.f = f;
  unsigned int u = x.u;
  return (u16)((u + 0x7fffu + ((u >> 16) & 1u)) >> 16);  // RNE
}

// ---------------- transpose + fp32->bf16 : out[n][k] = in[k][n] --------------
__global__ __launch_bounds__(256) void transpose_bf16(
    const float* __restrict__ in, u16* __restrict__ out, int rows, int cols) {
  __shared__ float tile[32][33];
  int bc = blockIdx.x * 32, br = blockIdx.y * 32;
  int tx = threadIdx.x & 31, ty = threadIdx.x >> 5;
  #pragma unroll
  for (int i = ty; i < 32; i += 8)
    tile[i][tx] = in[(size_t)(br + i) * cols + bc + tx];
  __syncthreads();
  #pragma unroll
  for (int i = ty; i < 32; i += 8)
    out[(size_t)(bc + i) * rows + br + tx] = f2bf(tile[tx][i]);
}

// ---------------- bias = u @ v : [1024,32]@[32,1024] fp32 --------------------
__global__ __launch_bounds__(256) void bias_lr(
    const float* __restrict__ u, const float* __restrict__ v,
    float* __restrict__ bias) {
  int m = blockIdx.x * 256 + threadIdx.x;
  int n = blockIdx.y;
  float acc = 0.f;
  #pragma unroll
  for (int r = 0; r < 32; ++r)
    acc += u[n * 32 + r] * v[r * 1024 + m];
  bias[(size_t)n * 1024 + m] = acc;
}

// ---------------- GEMM 64x64 tile, BK=64, 4 waves ----------------------------
// MODE 0: A = x fp32 [16384,512]; Bt = Wqkv^T bf16 [1536,512]; Out = qkv bf16
//         epilogue: + bqkv, elu+1 on cols<1024
// MODE 1: A = ob bf16 [16384,512]; Bt = Wout^T bf16 [512,512]; Out = fp32 d_out
template<int MODE>
__global__ __launch_bounds__(256) void gemm64(
    const void* __restrict__ Av, const u16* __restrict__ Bt,
    const float* __restrict__ bias, void* __restrict__ Out) {
  const int K = 512;
  const int NC = (MODE == 0) ? 1536 : 512;
  __shared__ __align__(16) u16 As[64 * 72];
  __shared__ __align__(16) u16 Bs[64 * 72];
  int tid = threadIdx.x;
  int w = tid >> 6, l = tid & 63, lo = l & 15, hi = l >> 4;
  int wr = (w >> 1) * 32, wc = (w & 1) * 32;
  int bm = blockIdx.y * 64, bn = blockIdx.x * 64;
  int sr = tid >> 2, sc = (tid & 3) * 16;   // staging: row, 16-wide col chunk

  f32x4 acc[2][2];
  #pragma unroll
  for (int i = 0; i < 2; ++i)
    #pragma unroll
    for (int j = 0; j < 2; ++j)
      acc[i][j] = (f32x4){0.f, 0.f, 0.f, 0.f};

  for (int k0 = 0; k0 < K; k0 += 64) {
    if (MODE == 0) {
      const float* A = (const float*)Av;
      const float* src = A + (size_t)(bm + sr) * K + k0 + sc;
      u16* dst = &As[sr * 72 + sc];
      #pragma unroll
      for (int q = 0; q < 4; ++q) {
        f32x4 f = *(const f32x4*)(src + q * 4);
        u16x4 pk;
        #pragma unroll
        for (int j = 0; j < 4; ++j) pk[j] = f2bf(f[j]);
        *(u16x4*)(dst + q * 4) = pk;
      }
    } else {
      const u16* A = (const u16*)Av;
      const u16* src = A + (size_t)(bm + sr) * K + k0 + sc;
      *(short8*)&As[sr * 72 + sc] = *(const short8*)src;
      *(short8*)&As[sr * 72 + sc + 8] = *(const short8*)(src + 8);
    }
    {
      const u16* src = Bt + (size_t)(bn + sr) * K + k0 + sc;
      *(short8*)&Bs[sr * 72 + sc] = *(const short8*)src;
      *(short8*)&Bs[sr * 72 + sc + 8] = *(const short8*)(src + 8);
    }
    __syncthreads();
    #pragma unroll
    for (int ks = 0; ks < 2; ++ks) {
      short8 a0 = *(const short8*)&As[(wr + lo) * 72 + ks * 32 + hi * 8];
      short8 a1 = *(const short8*)&As[(wr + 16 + lo) * 72 + ks * 32 + hi * 8];
      short8 b0 = *(const short8*)&Bs[(wc + lo) * 72 + ks * 32 + hi * 8];
      short8 b1 = *(const short8*)&Bs[(wc + 16 + lo) * 72 + ks * 32 + hi * 8];
      acc[0][0] = MFMA16(a0, b0, acc[0][0]);
      acc[0][1] = MFMA16(a0, b1, acc[0][1]);
      acc[1][0] = MFMA16(a1, b0, acc[1][0]);
      acc[1][1] = MFMA16(a1, b1, acc[1][1]);
    }
    __syncthreads();
  }
  #pragma unroll
  for (int i = 0; i < 2; ++i)
    #pragma unroll
    for (int j = 0; j < 2; ++j)
      #pragma unroll
      for (int r = 0; r < 4; ++r) {
        int row = bm + wr + i * 16 + hi * 4 + r;
        int col = bn + wc + j * 16 + lo;
        float v = acc[i][j][r] + bias[col];
        if (MODE == 0) {
          if (col < 1024) v = (v > 0.f) ? (v + 1.f) : __expf(v);
          ((u16*)Out)[(size_t)row * NC + col] = f2bf(v);
        } else {
          ((float*)Out)[(size_t)row * NC + col] = v;
        }
      }
}

// ---------------- flash attention: 4 waves x 16 q-rows, KV tile 64 -----------
// qkv bf16 [16384][1536]: cols [0,512)=q(elu+1 applied), [512,1024)=k, [1024,1536)=v
__global__ __launch_bounds__(256) void attn64(
    const u16* __restrict__ qkvb, const float* __restrict__ bias,
    u16* __restrict__ ob) {
  __shared__ __align__(16) u16 vt[64 * 72];      // [e][m] pad 72
  __shared__ __align__(16) u16 pl[4][16 * 72];   // per-wave P [qrow][m]
  int tid = threadIdx.x;
  int w = tid >> 6, l = tid & 63, lo = l & 15, hi = l >> 4;
  int bh = blockIdx.y, b = bh >> 3, h = bh & 7;
  int q0 = blockIdx.x * 64 + w * 16;

  const size_t rowQ = (size_t)(b * 1024 + q0 + lo) * 1536 + h * 64;
  short8 qf0 = *(const short8*)&qkvb[rowQ + hi * 8];
  short8 qf1 = *(const short8*)&qkvb[rowQ + 32 + hi * 8];

  f32x4 o[4];
  #pragma unroll
  for (int t = 0; t < 4; ++t) o[t] = (f32x4){0.f, 0.f, 0.f, 0.f};
  float mrun[4], lrun[4];
  #pragma unroll
  for (int r = 0; r < 4; ++r) { mrun[r] = -1e30f; lrun[r] = 0.f; }

  int sm = tid >> 2;          // m row 0..63 for V staging
  int se = (tid & 3) * 16;    // e chunk base

  for (int kv = 0; kv < 1024; kv += 64) {
    // stage V^T tile: vt[e][m] = v[kv+m][e]
    {
      const u16* vsrc = &qkvb[(size_t)(b * 1024 + kv + sm) * 1536 + 1024 + h * 64 + se];
      short8 v0 = *(const short8*)vsrc;
      short8 v1 = *(const short8*)(vsrc + 8);
      #pragma unroll
      for (int j = 0; j < 8; ++j) vt[(se + j) * 72 + sm] = (u16)v0[j];
      #pragma unroll
      for (int j = 0; j < 8; ++j) vt[(se + 8 + j) * 72 + sm] = (u16)v1[j];
    }
    // QK^T : S [16 q x 64 kv] as 4 sub-tiles
    f32x4 s[4];
    #pragma unroll
    for (int sub = 0; sub < 4; ++sub) {
      size_t rowK = (size_t)(b * 1024 + kv + sub * 16 + lo) * 1536 + 512 + h * 64;
      short8 kf0 = *(const short8*)&qkvb[rowK + hi * 8];
      short8 kf1 = *(const short8*)&qkvb[rowK + 32 + hi * 8];
      f32x4 z = (f32x4){0.f, 0.f, 0.f, 0.f};
      z = MFMA16(qf0, kf0, z);
      s[sub] = MFMA16(qf1, kf1, z);
    }
    // online softmax (rows: hi*4+r ; cols: sub*16+lo)
    float p[4][4];
    float alpha[4];
    #pragma unroll
    for (int r = 0; r < 4; ++r) {
      const float* bp = &bias[(size_t)(q0 + hi * 4 + r) * 1024 + kv + lo];
      float pm = -1e30f;
      #pragma unroll
      for (int sub = 0; sub < 4; ++sub) {
        float sv = s[sub][r] * 0.125f + bp[sub * 16];
        p[sub][r] = sv;
        pm = fmaxf(pm, sv);
      }
      pm = fmaxf(pm, __shfl_xor(pm, 1));
      pm = fmaxf(pm, __shfl_xor(pm, 2));
      pm = fmaxf(pm, __shfl_xor(pm, 4));
      pm = fmaxf(pm, __shfl_xor(pm, 8));
      float nm = fmaxf(mrun[r], pm);
      alpha[r] = __expf(mrun[r] - nm);
      mrun[r] = nm;
      float ps = 0.f;
      #pragma unroll
      for (int sub = 0; sub < 4; ++sub) {
        p[sub][r] = __expf(p[sub][r] - nm);
        ps += p[sub][r];
      }
      ps += __shfl_xor(ps, 1);
      ps += __shfl_xor(ps, 2);
      ps += __shfl_xor(ps, 4);
      ps += __shfl_xor(ps, 8);
      lrun[r] = lrun[r] * alpha[r] + ps;
    }
    #pragma unroll
    for (int t = 0; t < 4; ++t)
      #pragma unroll
      for (int r = 0; r < 4; ++r)
        o[t][r] *= alpha[r];
    // P -> LDS (D-layout scatter), reread as A-fragments
    #pragma unroll
    for (int sub = 0; sub < 4; ++sub)
      #pragma unroll
      for (int r = 0; r < 4; ++r)
        pl[w][(hi * 4 + r) * 72 + sub * 16 + lo] = f2bf(p[sub][r]);
    __syncthreads();   // vt + pl writes visible
    short8 pf0 = *(const short8*)&pl[w][lo * 72 + hi * 8];
    short8 pf1 = *(const short8*)&pl[w][lo * 72 + 32 + hi * 8];
    #pragma unroll
    for (int t = 0; t < 4; ++t) {
      short8 vf0 = *(const short8*)&vt[(t * 16 + lo) * 72 + hi * 8];
      short8 vf1 = *(const short8*)&vt[(t * 16 + lo) * 72 + 32 + hi * 8];
      o[t] = MFMA16(pf0, vf0, o[t]);
      o[t] = MFMA16(pf1, vf1, o[t]);
    }
    __syncthreads();   // reads done before next iter overwrites
  }
  // finalize: /l, write ob bf16 [16384][512]
  #pragma unroll
  for (int t = 0; t < 4; ++t)
    #pragma unroll
    for (int r = 0; r < 4; ++r) {
      float v = o[t][r] / lrun[r];
      int n = q0 + hi * 4 + r;
      ob[(size_t)(b * 1024 + n) * 512 + h * 64 + t * 16 + lo] = f2bf(v);
    }
}

extern "C" void kernel_launch(void* const* d_in, const int* in_sizes, int n_in,
                              void* d_out, int out_size, void* d_ws, size_t ws_size,
                              hipStream_t stream) {
  const float* x    = (const float*)d_in[0];   // [16384,512]
  const float* Wqkv = (const float*)d_in[1];   // [512,1536]
  const float* bqkv = (const float*)d_in[2];   // [1536]
  const float* Wout = (const float*)d_in[3];   // [512,512]
  const float* bout = (const float*)d_in[4];   // [512]
  const float* u    = (const float*)d_in[5];   // [1024,32]
  const float* vlr  = (const float*)d_in[6];   // [32,1024]
  float* out = (float*)d_out;

  char* ws = (char*)d_ws;
  u16*   qkvb   = (u16*)(ws);                         // 50,331,648 B
  u16*   Wqkvt  = (u16*)(ws + 50331648);              //  1,572,864 B
  u16*   Woutt  = (u16*)(ws + 50331648 + 1572864);    //    524,288 B
  float* biasws = (float*)(ws + 52428800);            //  4,194,304 B
  u16*   ob     = (u16*)(ws + 56623104);              // 16,777,216 B  (end 73,400,320)

  transpose_bf16<<<dim3(48, 16), 256, 0, stream>>>(Wqkv, Wqkvt, 512, 1536);
  transpose_bf16<<<dim3(16, 16), 256, 0, stream>>>(Wout, Woutt, 512, 512);
  bias_lr<<<dim3(4, 1024), 256, 0, stream>>>(u, vlr, biasws);
  gemm64<0><<<dim3(24, 256), 256, 0, stream>>>(x, Wqkvt, bqkv, qkvb);
  attn64<<<dim3(16, 128), 256, 0, stream>>>(qkvb, biasws, ob);
  gemm64<1><<<dim3(8, 256), 256, 0, stream>>>(ob, Woutt, bout, out);
}

// Round 2
// 249.751 us; speedup vs baseline: 1.4745x; 1.4745x over previous
//
#include <hip/hip_runtime.h>
#include <hip/hip_bf16.h>

typedef unsigned short u16;
typedef __attribute__((ext_vector_type(8))) short short8;
typedef __attribute__((ext_vector_type(4))) float f32x4;
typedef __attribute__((ext_vector_type(16))) float f32x16;
typedef __attribute__((ext_vector_type(4))) int i32x4;
typedef __attribute__((ext_vector_type(2))) int i32x2;

#define MFMA16(a,b,c) __builtin_amdgcn_mfma_f32_16x16x32_bf16((a),(b),(c),0,0,0)
#define MFMA32(a,b,c) __builtin_amdgcn_mfma_f32_32x32x16_bf16((a),(b),(c),0,0,0)

__device__ __forceinline__ u16 f2bf(float f) {
  union { float f; unsigned int u; } x; x.f = f;
  unsigned int u = x.u;
  return (u16)((u + 0x7fffu + ((u >> 16) & 1u)) >> 16);  // RNE
}

// v_cvt_pk_bf16_f32: dst = {hi: bf16(b), lo: bf16(a)}
__device__ __forceinline__ unsigned cvtpk(float a, float b) {
  unsigned r;
  asm("v_cvt_pk_bf16_f32 %0, %1, %2" : "=v"(r) : "v"(a), "v"(b));
  return r;
}

// async global->LDS, 16B per lane (dst = wave-uniform base + lane*16)
__device__ __forceinline__ void gld16(const void* g, void* l) {
  __builtin_amdgcn_global_load_lds(
      (const __attribute__((address_space(1))) void*)g,
      (__attribute__((address_space(3))) void*)l, 16, 0, 0);
}

// ---------------- fp32 -> bf16 convert (8 elems/thread) ----------------------
__global__ __launch_bounds__(256) void conv_bf16(
    const float* __restrict__ in, u16* __restrict__ out, int n8) {
  int i = blockIdx.x * 256 + threadIdx.x;
  if (i >= n8) return;
  f32x4 a = *(const f32x4*)(in + (size_t)i * 8);
  f32x4 b = *(const f32x4*)(in + (size_t)i * 8 + 4);
  union { short8 s; u16 u[8]; } r;
  #pragma unroll
  for (int j = 0; j < 4; ++j) { r.u[j] = f2bf(a[j]); r.u[4 + j] = f2bf(b[j]); }
  *(short8*)&out[(size_t)i * 8] = r.s;
}

// ---------------- transpose + fp32->bf16 : out[n][k] = in[k][n] --------------
__global__ __launch_bounds__(256) void transpose_bf16(
    const float* __restrict__ in, u16* __restrict__ out, int rows, int cols) {
  __shared__ float tile[32][33];
  int bc = blockIdx.x * 32, br = blockIdx.y * 32;
  int tx = threadIdx.x & 31, ty = threadIdx.x >> 5;
  #pragma unroll
  for (int i = ty; i < 32; i += 8)
    tile[i][tx] = in[(size_t)(br + i) * cols + bc + tx];
  __syncthreads();
  #pragma unroll
  for (int i = ty; i < 32; i += 8)
    out[(size_t)(bc + i) * rows + br + tx] = f2bf(tile[tx][i]);
}

// ---------------- V transpose per (b,h): [1024 n][64 e] -> [64 e][1024 n] ----
__global__ __launch_bounds__(256) void vtrans(
    const u16* __restrict__ in, u16* __restrict__ out) {
  __shared__ u16 t[32][33];
  int bh = blockIdx.z;
  int n0 = blockIdx.y * 32, e0 = blockIdx.x * 32;
  int tx = threadIdx.x & 31, ty = threadIdx.x >> 5;
  size_t base = (size_t)bh << 16;
  #pragma unroll
  for (int i = ty; i < 32; i += 8)
    t[i][tx] = in[base + (size_t)(n0 + i) * 64 + e0 + tx];
  __syncthreads();
  #pragma unroll
  for (int i = ty; i < 32; i += 8)
    out[base + (size_t)(e0 + i) * 1024 + n0 + tx] = t[tx][i];
}

// ---------------- GEMM 128x128 tile, BK=64, 4 waves, global_load_lds ---------
// MODE 0: A=xb bf16 [16384,512], Bt=Wqkvt [1536,512]; epilogue: +bqkv,
//         q: (elu+1)*0.125 -> qh[bh][n][64]; k: elu+1 -> kh; v: raw -> vtmp
// MODE 1: A=ob bf16 [16384,512], Bt=Woutt [512,512]; +bout -> fp32 out
template<int MODE>
__global__ __launch_bounds__(256) void gemm128(
    const u16* __restrict__ A, const u16* __restrict__ Bt,
    const float* __restrict__ bias,
    u16* __restrict__ oq, u16* __restrict__ ok, u16* __restrict__ ov,
    float* __restrict__ fo) {
  const int K = 512;
  __shared__ __align__(16) u16 As[128 * 64];
  __shared__ __align__(16) u16 Bs[128 * 64];
  int tid = threadIdx.x;
  int w = tid >> 6, ln = tid & 63, lo = ln & 15, hi = ln >> 4;
  int wr = (w >> 1) * 64, wc = (w & 1) * 64;
  int bm = blockIdx.y * 128, bn = blockIdx.x * 128;

  f32x4 acc[4][4];
  #pragma unroll
  for (int m = 0; m < 4; ++m)
    #pragma unroll
    for (int n = 0; n < 4; ++n)
      acc[m][n] = (f32x4){0.f, 0.f, 0.f, 0.f};

  for (int k0 = 0; k0 < K; k0 += 64) {
    #pragma unroll
    for (int i = 0; i < 4; ++i) {
      int c = i * 256 + w * 64 + ln;
      int r = c >> 3, cc = c & 7;
      gld16(&A[(size_t)(bm + r) * K + k0 + ((cc ^ (r & 7)) << 3)], &As[c << 3]);
    }
    #pragma unroll
    for (int i = 0; i < 4; ++i) {
      int c = i * 256 + w * 64 + ln;
      int r = c >> 3, cc = c & 7;
      gld16(&Bt[(size_t)(bn + r) * K + k0 + ((cc ^ (r & 7)) << 3)], &Bs[c << 3]);
    }
    __syncthreads();
    #pragma unroll
    for (int ks = 0; ks < 2; ++ks) {
      short8 a[4], b[4];
      #pragma unroll
      for (int m = 0; m < 4; ++m) {
        int row = wr + m * 16 + lo;
        a[m] = *(const short8*)&As[row * 64 + (((ks * 4 + hi) ^ (lo & 7)) << 3)];
      }
      #pragma unroll
      for (int n = 0; n < 4; ++n) {
        int row = wc + n * 16 + lo;
        b[n] = *(const short8*)&Bs[row * 64 + (((ks * 4 + hi) ^ (lo & 7)) << 3)];
      }
      #pragma unroll
      for (int m = 0; m < 4; ++m)
        #pragma unroll
        for (int n = 0; n < 4; ++n)
          acc[m][n] = MFMA16(a[m], b[n], acc[m][n]);
    }
    __syncthreads();
  }
  #pragma unroll
  for (int m = 0; m < 4; ++m)
    #pragma unroll
    for (int n = 0; n < 4; ++n)
      #pragma unroll
      for (int r = 0; r < 4; ++r) {
        int row = bm + wr + m * 16 + hi * 4 + r;
        int col = bn + wc + n * 16 + lo;
        float v = acc[m][n][r] + bias[col];
        if (MODE == 0) {
          int type = col >> 9, hd = (col >> 6) & 7, e = col & 63;
          if (type < 2) { v = (v > 0.f) ? (v + 1.f) : __expf(v); if (type == 0) v *= 0.125f; }
          u16* dst = (type == 0) ? oq : ((type == 1) ? ok : ov);
          dst[(size_t)(((row >> 10) << 3) + hd) * 65536 + (size_t)(row & 1023) * 64 + e] = f2bf(v);
        } else {
          fo[(size_t)row * 512 + col] = v;
        }
      }
}

// ---------------- flash attention: 4 waves x 32 q-rows, swapped 32x32 MFMA ---
// qh/kh [bh][1024][64] bf16 (q pre: (elu+1)/8); vt [bh][64][1024] bf16 (V^T)
// ub [1024][32] bf16 (u); vtb [1024][32] bf16 (v^T). S^T = K*Q + vtb*ub.
__global__ __launch_bounds__(256) void attn32(
    const u16* __restrict__ qh, const u16* __restrict__ kh,
    const u16* __restrict__ vt, const u16* __restrict__ ub,
    const u16* __restrict__ vtb, u16* __restrict__ ob) {
  __shared__ __align__(16) u16 Ks[64 * 64];   // [m][d], chunk-swizzled
  __shared__ __align__(16) u16 Vs[64 * 64];   // [e][m], chunk-swizzled
  __shared__ __align__(16) u16 Tb[64 * 32];   // [m][r], chunk-swizzled
  int tid = threadIdx.x;
  int w = tid >> 6, ln = tid & 63;
  int m32 = ln & 31, h = ln >> 5;
  int bh = blockIdx.y;
  int q0 = blockIdx.x * 128 + w * 32;
  size_t bhb = (size_t)bh << 16;

  short8 qf[4], uf[2];
  #pragma unroll
  for (int ks = 0; ks < 4; ++ks)
    qf[ks] = *(const short8*)&qh[bhb + (size_t)(q0 + m32) * 64 + ks * 16 + h * 8];
  #pragma unroll
  for (int k2 = 0; k2 < 2; ++k2)
    uf[k2] = *(const short8*)&ub[(size_t)(q0 + m32) * 32 + k2 * 16 + h * 8];

  f32x16 o0 = {0.f,0.f,0.f,0.f,0.f,0.f,0.f,0.f,0.f,0.f,0.f,0.f,0.f,0.f,0.f,0.f};
  f32x16 o1 = o0;
  float mrun = -3e38f, lrun = 0.f;

  for (int kv = 0; kv < 1024; kv += 64) {
    // ---- stage K tile [64][64], V^T tile [64][64], v^T-bias tile [64][32]
    #pragma unroll
    for (int i = 0; i < 2; ++i) {
      int c = i * 256 + w * 64 + ln;
      int r = c >> 3, cc = c & 7;
      gld16(&kh[bhb + (size_t)(kv + r) * 64 + ((cc ^ (r & 7)) << 3)], &Ks[c << 3]);
    }
    #pragma unroll
    for (int i = 0; i < 2; ++i) {
      int c = i * 256 + w * 64 + ln;
      int r = c >> 3, cc = c & 7;
      gld16(&vt[bhb + (size_t)r * 1024 + kv + ((cc ^ (r & 7)) << 3)], &Vs[c << 3]);
    }
    {
      int c = w * 64 + ln;
      int r = c >> 2, cc = c & 3;
      gld16(&vtb[(size_t)(kv + r) * 32 + ((cc ^ (r & 3)) << 3)], &Tb[c << 3]);
    }
    __syncthreads();

    // ---- S^T = vtb*ub + K*Q  (two 32-row kv tiles; lane: col q=m32, 16 rows)
    f32x16 s0 = {0.f,0.f,0.f,0.f,0.f,0.f,0.f,0.f,0.f,0.f,0.f,0.f,0.f,0.f,0.f,0.f};
    f32x16 s1 = s0;
    #pragma unroll
    for (int k2 = 0; k2 < 2; ++k2) {
      int r0 = m32, r1 = 32 + m32;
      short8 t0 = *(const short8*)&Tb[r0 * 32 + (((k2 * 2 + h) ^ (r0 & 3)) << 3)];
      short8 t1 = *(const short8*)&Tb[r1 * 32 + (((k2 * 2 + h) ^ (r1 & 3)) << 3)];
      s0 = MFMA32(t0, uf[k2], s0);
      s1 = MFMA32(t1, uf[k2], s1);
    }
    #pragma unroll
    for (int ks = 0; ks < 4; ++ks) {
      int r0 = m32, r1 = 32 + m32;
      short8 k0f = *(const short8*)&Ks[r0 * 64 + (((ks * 2 + h) ^ (r0 & 7)) << 3)];
      short8 k1f = *(const short8*)&Ks[r1 * 64 + (((ks * 2 + h) ^ (r1 & 7)) << 3)];
      s0 = MFMA32(k0f, qf[ks], s0);
      s1 = MFMA32(k1f, qf[ks], s1);
    }

    // ---- online softmax: q is lane-local; 1 shuffle for cross-half max
    float pm = fmaxf(s0[0], s1[0]);
    #pragma unroll
    for (int i = 1; i < 16; ++i) pm = fmaxf(pm, fmaxf(s0[i], s1[i]));
    pm = fmaxf(pm, __shfl_xor(pm, 32));
    if (__ballot(pm > mrun)) {
      float nm = fmaxf(mrun, pm);
      float al = __expf(mrun - nm);
      #pragma unroll
      for (int i = 0; i < 16; ++i) { o0[i] *= al; o1[i] *= al; }
      lrun *= al;
      mrun = nm;
    }
    float ls = 0.f;
    #pragma unroll
    for (int i = 0; i < 16; ++i) { float p = __expf(s0[i] - mrun); s0[i] = p; ls += p; }
    #pragma unroll
    for (int i = 0; i < 16; ++i) { float p = __expf(s1[i] - mrun); s1[i] = p; ls += p; }
    lrun += ls;

    // ---- pack P^T to bf16 and build PV B-frags via permlane32_swap
    unsigned pk0[4][2], pk1[4][2];
    #pragma unroll
    for (int r8 = 0; r8 < 4; ++r8) {
      pk0[r8][0] = cvtpk(s0[r8 * 4 + 0], s0[r8 * 4 + 1]);
      pk0[r8][1] = cvtpk(s0[r8 * 4 + 2], s0[r8 * 4 + 3]);
      pk1[r8][0] = cvtpk(s1[r8 * 4 + 0], s1[r8 * 4 + 1]);
      pk1[r8][1] = cvtpk(s1[r8 * 4 + 2], s1[r8 * 4 + 3]);
    }
    #pragma unroll
    for (int kvt = 0; kvt < 2; ++kvt) {
      #pragma unroll
      for (int msl = 0; msl < 2; ++msl) {
        unsigned a0 = kvt ? pk1[2 * msl][0] : pk0[2 * msl][0];
        unsigned b0 = kvt ? pk1[2 * msl + 1][0] : pk0[2 * msl + 1][0];
        unsigned a1 = kvt ? pk1[2 * msl][1] : pk0[2 * msl][1];
        unsigned b1 = kvt ? pk1[2 * msl + 1][1] : pk0[2 * msl + 1][1];
        asm("v_permlane32_swap_b32 %0, %1" : "+v"(a0), "+v"(b0));
        asm("v_permlane32_swap_b32 %0, %1" : "+v"(a1), "+v"(b1));
        union { i32x4 i; short8 s; } pu;
        pu.i = (i32x4){(int)a0, (int)a1, (int)b0, (int)b1};
        int ms = kvt * 2 + msl;
        int r0 = m32, r1 = 32 + m32;
        short8 v0 = *(const short8*)&Vs[r0 * 64 + (((ms * 2 + h) ^ (r0 & 7)) << 3)];
        short8 v1 = *(const short8*)&Vs[r1 * 64 + (((ms * 2 + h) ^ (r1 & 7)) << 3)];
        o0 = MFMA32(v0, pu.s, o0);
        o1 = MFMA32(v1, pu.s, o1);
      }
    }
    __syncthreads();
  }

  // ---- finalize: O^T lane holds q=m32 col, e rows; divide by l, store bf16
  float lt = lrun + __shfl_xor(lrun, 32);
  float li = 1.f / lt;
  int b = bh >> 3, hd = bh & 7;
  size_t orow = ((size_t)(b * 1024 + q0 + m32)) * 512 + hd * 64;
  #pragma unroll
  for (int et = 0; et < 2; ++et) {
    #pragma unroll
    for (int r8 = 0; r8 < 4; ++r8) {
      float v0 = (et ? o1[r8 * 4 + 0] : o0[r8 * 4 + 0]) * li;
      float v1 = (et ? o1[r8 * 4 + 1] : o0[r8 * 4 + 1]) * li;
      float v2 = (et ? o1[r8 * 4 + 2] : o0[r8 * 4 + 2]) * li;
      float v3 = (et ? o1[r8 * 4 + 3] : o0[r8 * 4 + 3]) * li;
      i32x2 d = {(int)cvtpk(v0, v1), (int)cvtpk(v2, v3)};
      *(i32x2*)&ob[orow + et * 32 + 8 * r8 + 4 * h] = d;
    }
  }
}

extern "C" void kernel_launch(void* const* d_in, const int* in_sizes, int n_in,
                              void* d_out, int out_size, void* d_ws, size_t ws_size,
                              hipStream_t stream) {
  const float* x    = (const float*)d_in[0];   // [16384,512]
  const float* Wqkv = (const float*)d_in[1];   // [512,1536]
  const float* bqkv = (const float*)d_in[2];   // [1536]
  const float* Wout = (const float*)d_in[3];   // [512,512]
  const float* bout = (const float*)d_in[4];   // [512]
  const float* u    = (const float*)d_in[5];   // [1024,32]
  const float* vlr  = (const float*)d_in[6];   // [32,1024]
  float* out = (float*)d_out;

  char* ws = (char*)d_ws;
  u16* qh    = (u16*)(ws);                      // 16 MB  [bh][n][64]
  u16* kh    = (u16*)(ws + 16777216);           // 16 MB  [bh][n][64]
  u16* xb    = (u16*)(ws + 33554432);           // 16 MB  (xb, then vT reuses)
  u16* vTg   = (u16*)(ws + 33554432);           // 16 MB  [bh][64][1024]
  u16* vtmp  = (u16*)(ws + 50331648);           // 16 MB  (vtmp, then ob reuses)
  u16* ob    = (u16*)(ws + 50331648);           // 16 MB  [n][512]
  u16* Wqkvt = (u16*)(ws + 67108864);           // 1.5 MB [1536][512]
  u16* Woutt = (u16*)(ws + 68681728);           // 0.5 MB [512][512]
  u16* ub    = (u16*)(ws + 69206016);           // 64 KB  [1024][32]
  u16* vTb   = (u16*)(ws + 69271552);           // 64 KB  [1024][32]

  conv_bf16<<<4096, 256, 0, stream>>>(x, xb, 1048576);
  conv_bf16<<<16, 256, 0, stream>>>(u, ub, 4096);
  transpose_bf16<<<dim3(48, 16), 256, 0, stream>>>(Wqkv, Wqkvt, 512, 1536);
  transpose_bf16<<<dim3(16, 16), 256, 0, stream>>>(Wout, Woutt, 512, 512);
  transpose_bf16<<<dim3(32, 1), 256, 0, stream>>>(vlr, vTb, 32, 1024);
  gemm128<0><<<dim3(12, 128), 256, 0, stream>>>(xb, Wqkvt, bqkv, qh, kh, vtmp, nullptr);
  vtrans<<<dim3(2, 32, 128), 256, 0, stream>>>(vtmp, vTg);
  attn32<<<dim3(8, 128), 256, 0, stream>>>(qh, kh, vTg, ub, vTb, ob);
  gemm128<1><<<dim3(4, 128), 256, 0, stream>>>(ob, Woutt, bout, nullptr, nullptr, nullptr, out);
}

// Round 4
// 220.504 us; speedup vs baseline: 1.6701x; 1.1326x over previous
//
#include <hip/hip_runtime.h>
#include <hip/hip_bf16.h>

typedef unsigned short u16;
typedef __attribute__((ext_vector_type(8))) short short8;
typedef __attribute__((ext_vector_type(4))) float f32x4;
typedef __attribute__((ext_vector_type(16))) float f32x16;
typedef __attribute__((ext_vector_type(4))) int i32x4;
typedef __attribute__((ext_vector_type(2))) int i32x2;

#define MFMA16(a,b,c) __builtin_amdgcn_mfma_f32_16x16x32_bf16((a),(b),(c),0,0,0)
#define MFMA32(a,b,c) __builtin_amdgcn_mfma_f32_32x32x16_bf16((a),(b),(c),0,0,0)

__device__ __forceinline__ u16 f2bf(float f) {
  union { float f; unsigned int u; } x; x.f = f;
  unsigned int u = x.u;
  return (u16)((u + 0x7fffu + ((u >> 16) & 1u)) >> 16);  // RNE
}

// v_cvt_pk_bf16_f32: dst = {hi: bf16(b), lo: bf16(a)}
__device__ __forceinline__ unsigned cvtpk(float a, float b) {
  unsigned r;
  asm("v_cvt_pk_bf16_f32 %0, %1, %2" : "=v"(r) : "v"(a), "v"(b));
  return r;
}

// v_exp_f32: 2^x
__device__ __forceinline__ float exp2v(float x) {
  float r;
  asm("v_exp_f32 %0, %1" : "=v"(r) : "v"(x));
  return r;
}

// async global->LDS, 16B per lane (dst = wave-uniform base + lane*16)
__device__ __forceinline__ void gld16(const void* g, void* l) {
  __builtin_amdgcn_global_load_lds(
      (const __attribute__((address_space(1))) void*)g,
      (__attribute__((address_space(3))) void*)l, 16, 0, 0);
}

// ---------------- fused preprocessing ----------------------------------------
// blocks [0,4096): x fp32 -> xb bf16            (8 elems/thread)
// blocks [4096,4112): u fp32 *log2e -> ub bf16
// blocks [4112,4880): Wqkv transpose -> Wqkvt [1536][512]
// blocks [4880,5136): Wout transpose -> Woutt [512][512]
// blocks [5136,5168): vlr  transpose -> vTb   [1024][32]
__global__ __launch_bounds__(256) void prep(
    const float* __restrict__ x, u16* __restrict__ xb,
    const float* __restrict__ u, u16* __restrict__ ub,
    const float* __restrict__ Wqkv, u16* __restrict__ Wqkvt,
    const float* __restrict__ Wout, u16* __restrict__ Woutt,
    const float* __restrict__ vlr, u16* __restrict__ vTb) {
  __shared__ float tile[32][33];
  int bid = blockIdx.x, tid = threadIdx.x;
  if (bid < 4112) {
    const float* in; u16* out; size_t i; float sc;
    if (bid < 4096) { in = x; out = xb; i = (size_t)bid * 256 + tid; sc = 1.f; }
    else { in = u; out = ub; i = (size_t)(bid - 4096) * 256 + tid; sc = 1.44269504f; }
    f32x4 a = *(const f32x4*)(in + i * 8);
    f32x4 b = *(const f32x4*)(in + i * 8 + 4);
    union { short8 s; u16 us[8]; } r;
    #pragma unroll
    for (int j = 0; j < 4; ++j) { r.us[j] = f2bf(a[j] * sc); r.us[4 + j] = f2bf(b[j] * sc); }
    *(short8*)&out[i * 8] = r.s;
    return;
  }
  int tb = bid - 4112;
  const float* in; u16* out; int rows, cols, bx, by;
  if (tb < 768)       { in = Wqkv; out = Wqkvt; rows = 512; cols = 1536; bx = tb % 48; by = tb / 48; }
  else if (tb < 1024) { int q = tb - 768; in = Wout; out = Woutt; rows = 512; cols = 512; bx = q % 16; by = q / 16; }
  else                { in = vlr; out = vTb; rows = 32; cols = 1024; bx = tb - 1024; by = 0; }
  int bc = bx * 32, br = by * 32;
  int tx = tid & 31, ty = tid >> 5;
  #pragma unroll
  for (int i = ty; i < 32; i += 8)
    tile[i][tx] = in[(size_t)(br + i) * cols + bc + tx];
  __syncthreads();
  #pragma unroll
  for (int i = ty; i < 32; i += 8)
    out[(size_t)(bc + i) * rows + br + tx] = f2bf(tile[tx][i]);
}

// ---------------- V transpose per (b,h): [1024 n][64 e] -> [64 e][1024 n] ----
__global__ __launch_bounds__(256) void vtrans(
    const u16* __restrict__ in, u16* __restrict__ out) {
  __shared__ u16 t[32][33];
  int bh = blockIdx.z;
  int n0 = blockIdx.y * 32, e0 = blockIdx.x * 32;
  int tx = threadIdx.x & 31, ty = threadIdx.x >> 5;
  size_t base = (size_t)bh << 16;
  #pragma unroll
  for (int i = ty; i < 32; i += 8)
    t[i][tx] = in[base + (size_t)(n0 + i) * 64 + e0 + tx];
  __syncthreads();
  #pragma unroll
  for (int i = ty; i < 32; i += 8)
    out[base + (size_t)(e0 + i) * 1024 + n0 + tx] = t[tx][i];
}

// ---------------- GEMM 128x128 tile, BK=64, 4 waves, global_load_lds ---------
// MODE 0: A=xb bf16 [16384,512], Bt=Wqkvt [1536,512]; epilogue: +bqkv,
//         q: (elu+1)*0.125*log2e -> qh[bh][n][64]; k: elu+1 -> kh; v -> vtmp
// MODE 1: A=ob bf16 [16384,512], Bt=Woutt [512,512]; +bout -> fp32 out
template<int MODE>
__global__ __launch_bounds__(256) void gemm128(
    const u16* __restrict__ A, const u16* __restrict__ Bt,
    const float* __restrict__ bias,
    u16* __restrict__ oq, u16* __restrict__ ok, u16* __restrict__ ov,
    float* __restrict__ fo) {
  const int K = 512;
  __shared__ __align__(16) u16 As[128 * 64];
  __shared__ __align__(16) u16 Bs[128 * 64];
  int tid = threadIdx.x;
  int w = tid >> 6, ln = tid & 63, lo = ln & 15, hi = ln >> 4;
  int wr = (w >> 1) * 64, wc = (w & 1) * 64;
  // XCD-chunked bijective swizzle (gridDim.y % 8 == 0)
  int lin = blockIdx.y * gridDim.x + blockIdx.x;
  int xcd = lin & 7, idx = lin >> 3;
  int perx = gridDim.x, rows_per = gridDim.y >> 3;
  int by = xcd * rows_per + idx / perx;
  int bx = idx % perx;
  int bm = by * 128, bn = bx * 128;

  f32x4 acc[4][4];
  #pragma unroll
  for (int m = 0; m < 4; ++m)
    #pragma unroll
    for (int n = 0; n < 4; ++n)
      acc[m][n] = (f32x4){0.f, 0.f, 0.f, 0.f};

  for (int k0 = 0; k0 < K; k0 += 64) {
    #pragma unroll
    for (int i = 0; i < 4; ++i) {
      int c = i * 256 + w * 64 + ln;
      int r = c >> 3, cc = c & 7;
      gld16(&A[(size_t)(bm + r) * K + k0 + ((cc ^ (r & 7)) << 3)], &As[c << 3]);
    }
    #pragma unroll
    for (int i = 0; i < 4; ++i) {
      int c = i * 256 + w * 64 + ln;
      int r = c >> 3, cc = c & 7;
      gld16(&Bt[(size_t)(bn + r) * K + k0 + ((cc ^ (r & 7)) << 3)], &Bs[c << 3]);
    }
    __syncthreads();
    #pragma unroll
    for (int ks = 0; ks < 2; ++ks) {
      short8 a[4], b[4];
      #pragma unroll
      for (int m = 0; m < 4; ++m) {
        int row = wr + m * 16 + lo;
        a[m] = *(const short8*)&As[row * 64 + (((ks * 4 + hi) ^ (lo & 7)) << 3)];
      }
      #pragma unroll
      for (int n = 0; n < 4; ++n) {
        int row = wc + n * 16 + lo;
        b[n] = *(const short8*)&Bs[row * 64 + (((ks * 4 + hi) ^ (lo & 7)) << 3)];
      }
      #pragma unroll
      for (int m = 0; m < 4; ++m)
        #pragma unroll
        for (int n = 0; n < 4; ++n)
          acc[m][n] = MFMA16(a[m], b[n], acc[m][n]);
    }
    __syncthreads();
  }
  #pragma unroll
  for (int m = 0; m < 4; ++m)
    #pragma unroll
    for (int n = 0; n < 4; ++n)
      #pragma unroll
      for (int r = 0; r < 4; ++r) {
        int row = bm + wr + m * 16 + hi * 4 + r;
        int col = bn + wc + n * 16 + lo;
        float v = acc[m][n][r] + bias[col];
        if (MODE == 0) {
          int type = col >> 9, hd = (col >> 6) & 7, e = col & 63;
          if (type < 2) {
            v = (v > 0.f) ? (v + 1.f) : __expf(v);
            if (type == 0) v *= 0.18033688f;   // 0.125 * log2(e)
          }
          u16* dst = (type == 0) ? oq : ((type == 1) ? ok : ov);
          dst[(size_t)(((row >> 10) << 3) + hd) * 65536 + (size_t)(row & 1023) * 64 + e] = f2bf(v);
        } else {
          fo[(size_t)row * 512 + col] = v;
        }
      }
}

// ---------------- flash attention: double-buffered 2-phase, swapped 32x32 ----
// qh/kh [bh][1024][64] bf16 (q pre: (elu+1)/8*log2e); vt [bh][64][1024] (V^T)
// ub [1024][32] bf16 (u*log2e); vtb [1024][32] bf16 (v^T). S' = log2e*(qk/8+bias).
__global__ __launch_bounds__(256, 4) void attn32(
    const u16* __restrict__ qh, const u16* __restrict__ kh,
    const u16* __restrict__ vt, const u16* __restrict__ ub,
    const u16* __restrict__ vtb, u16* __restrict__ ob) {
  __shared__ __align__(16) u16 Ks[2][64 * 64];   // [m][d], chunk-swizzled
  __shared__ __align__(16) u16 Vs[2][64 * 64];   // [e][m], chunk-swizzled
  __shared__ __align__(16) u16 Tb[2][64 * 32];   // [m][r], chunk-swizzled
  int tid = threadIdx.x;
  int w = tid >> 6, ln = tid & 63;
  int m32 = ln & 31, h = ln >> 5;
  // XCD swizzle: 16 contiguous bh per XCD -> K/V panels L2-resident per XCD
  int lin = blockIdx.y * 8 + blockIdx.x;
  int xcd = lin & 7, idx = lin >> 3;           // idx in [0,128)
  int bh = xcd * 16 + (idx >> 3);
  int q0 = (idx & 7) * 128 + w * 32;
  size_t bhb = (size_t)bh << 16;

  short8 qf[4], uf[2];
  #pragma unroll
  for (int ks = 0; ks < 4; ++ks)
    qf[ks] = *(const short8*)&qh[bhb + (size_t)(q0 + m32) * 64 + ks * 16 + h * 8];
  #pragma unroll
  for (int k2 = 0; k2 < 2; ++k2)
    uf[k2] = *(const short8*)&ub[(size_t)(q0 + m32) * 32 + k2 * 16 + h * 8];

  auto STAGE = [&](int buf, int kv) {
    #pragma unroll
    for (int i = 0; i < 2; ++i) {
      int c = i * 256 + w * 64 + ln;
      int r = c >> 3, cc = c & 7;
      gld16(&kh[bhb + (size_t)(kv + r) * 64 + ((cc ^ (r & 7)) << 3)], &Ks[buf][c << 3]);
    }
    #pragma unroll
    for (int i = 0; i < 2; ++i) {
      int c = i * 256 + w * 64 + ln;
      int r = c >> 3, cc = c & 7;
      gld16(&vt[bhb + (size_t)r * 1024 + kv + ((cc ^ (r & 7)) << 3)], &Vs[buf][c << 3]);
    }
    {
      int c = w * 64 + ln;
      int r = c >> 2, cc = c & 3;
      gld16(&vtb[(size_t)(kv + r) * 32 + ((cc ^ (r & 3)) << 3)], &Tb[buf][c << 3]);
    }
  };

  f32x16 o0 = {0.f,0.f,0.f,0.f,0.f,0.f,0.f,0.f,0.f,0.f,0.f,0.f,0.f,0.f,0.f,0.f};
  f32x16 o1 = o0;
  float mrun = -3e38f, lrun = 0.f;

  int cur = 0;
  STAGE(0, 0);
  __syncthreads();

  for (int t = 0; t < 16; ++t) {
    // prefetch next tile into the other buffer; latency hides under compute
    if (t < 15) STAGE(cur ^ 1, (t + 1) * 64);

    // ---- S'^T = vtb*ub + K*Q  (lane: col q=m32; 16 kv-rows per half)
    f32x16 s0 = {0.f,0.f,0.f,0.f,0.f,0.f,0.f,0.f,0.f,0.f,0.f,0.f,0.f,0.f,0.f,0.f};
    f32x16 s1 = s0;
    __builtin_amdgcn_s_setprio(1);
    #pragma unroll
    for (int k2 = 0; k2 < 2; ++k2) {
      int r0 = m32, r1 = 32 + m32;
      short8 t0 = *(const short8*)&Tb[cur][r0 * 32 + (((k2 * 2 + h) ^ (r0 & 3)) << 3)];
      short8 t1 = *(const short8*)&Tb[cur][r1 * 32 + (((k2 * 2 + h) ^ (r1 & 3)) << 3)];
      s0 = MFMA32(t0, uf[k2], s0);
      s1 = MFMA32(t1, uf[k2], s1);
    }
    #pragma unroll
    for (int ks = 0; ks < 4; ++ks) {
      int r0 = m32, r1 = 32 + m32;
      short8 k0f = *(const short8*)&Ks[cur][r0 * 64 + (((ks * 2 + h) ^ (r0 & 7)) << 3)];
      short8 k1f = *(const short8*)&Ks[cur][r1 * 64 + (((ks * 2 + h) ^ (r1 & 7)) << 3)];
      s0 = MFMA32(k0f, qf[ks], s0);
      s1 = MFMA32(k1f, qf[ks], s1);
    }
    __builtin_amdgcn_s_setprio(0);

    // ---- online softmax in exp2 domain; defer-max (THR = 8*log2e)
    float pm = fmaxf(s0[0], s1[0]);
    #pragma unroll
    for (int i = 1; i < 16; ++i) pm = fmaxf(pm, fmaxf(s0[i], s1[i]));
    pm = fmaxf(pm, __shfl_xor(pm, 32));
    if (!__all(pm - mrun <= 11.5f)) {
      float nm = fmaxf(mrun, pm);
      float al = exp2v(mrun - nm);
      #pragma unroll
      for (int i = 0; i < 16; ++i) { o0[i] *= al; o1[i] *= al; }
      lrun *= al;
      mrun = nm;
    }
    float ls = 0.f;
    #pragma unroll
    for (int i = 0; i < 16; ++i) { float p = exp2v(s0[i] - mrun); s0[i] = p; ls += p; }
    #pragma unroll
    for (int i = 0; i < 16; ++i) { float p = exp2v(s1[i] - mrun); s1[i] = p; ls += p; }
    lrun += ls;

    // ---- pack P^T to bf16, build PV B-frags via permlane32_swap
    unsigned pk0[4][2], pk1[4][2];
    #pragma unroll
    for (int r8 = 0; r8 < 4; ++r8) {
      pk0[r8][0] = cvtpk(s0[r8 * 4 + 0], s0[r8 * 4 + 1]);
      pk0[r8][1] = cvtpk(s0[r8 * 4 + 2], s0[r8 * 4 + 3]);
      pk1[r8][0] = cvtpk(s1[r8 * 4 + 0], s1[r8 * 4 + 1]);
      pk1[r8][1] = cvtpk(s1[r8 * 4 + 2], s1[r8 * 4 + 3]);
    }
    #pragma unroll
    for (int kvt = 0; kvt < 2; ++kvt) {
      #pragma unroll
      for (int msl = 0; msl < 2; ++msl) {
        unsigned a0 = kvt ? pk1[2 * msl][0] : pk0[2 * msl][0];
        unsigned b0 = kvt ? pk1[2 * msl + 1][0] : pk0[2 * msl + 1][0];
        unsigned a1 = kvt ? pk1[2 * msl][1] : pk0[2 * msl][1];
        unsigned b1 = kvt ? pk1[2 * msl + 1][1] : pk0[2 * msl + 1][1];
        asm("v_permlane32_swap_b32 %0, %1" : "+v"(a0), "+v"(b0));
        asm("v_permlane32_swap_b32 %0, %1" : "+v"(a1), "+v"(b1));
        union { i32x4 i; short8 s; } pu;
        pu.i = (i32x4){(int)a0, (int)a1, (int)b0, (int)b1};
        int ms = kvt * 2 + msl;
        int r0 = m32, r1 = 32 + m32;
        short8 v0 = *(const short8*)&Vs[cur][r0 * 64 + (((ms * 2 + h) ^ (r0 & 7)) << 3)];
        short8 v1 = *(const short8*)&Vs[cur][r1 * 64 + (((ms * 2 + h) ^ (r1 & 7)) << 3)];
        __builtin_amdgcn_s_setprio(1);
        o0 = MFMA32(v0, pu.s, o0);
        o1 = MFMA32(v1, pu.s, o1);
        __builtin_amdgcn_s_setprio(0);
      }
    }
    __syncthreads();   // drains prefetch vmcnt + all ds reads of buf[cur]
    cur ^= 1;
  }

  // ---- finalize: O^T lane holds q=m32 col, e rows; divide by l, store bf16
  float lt = lrun + __shfl_xor(lrun, 32);
  float li = 1.f / lt;
  int b = bh >> 3, hd = bh & 7;
  size_t orow = ((size_t)(b * 1024 + q0 + m32)) * 512 + hd * 64;
  #pragma unroll
  for (int et = 0; et < 2; ++et) {
    #pragma unroll
    for (int r8 = 0; r8 < 4; ++r8) {
      float v0 = (et ? o1[r8 * 4 + 0] : o0[r8 * 4 + 0]) * li;
      float v1 = (et ? o1[r8 * 4 + 1] : o0[r8 * 4 + 1]) * li;
      float v2 = (et ? o1[r8 * 4 + 2] : o0[r8 * 4 + 2]) * li;
      float v3 = (et ? o1[r8 * 4 + 3] : o0[r8 * 4 + 3]) * li;
      i32x2 d = {(int)cvtpk(v0, v1), (int)cvtpk(v2, v3)};
      *(i32x2*)&ob[orow + et * 32 + 8 * r8 + 4 * h] = d;
    }
  }
}

extern "C" void kernel_launch(void* const* d_in, const int* in_sizes, int n_in,
                              void* d_out, int out_size, void* d_ws, size_t ws_size,
                              hipStream_t stream) {
  const float* x    = (const float*)d_in[0];   // [16384,512]
  const float* Wqkv = (const float*)d_in[1];   // [512,1536]
  const float* bqkv = (const float*)d_in[2];   // [1536]
  const float* Wout = (const float*)d_in[3];   // [512,512]
  const float* bout = (const float*)d_in[4];   // [512]
  const float* u    = (const float*)d_in[5];   // [1024,32]
  const float* vlr  = (const float*)d_in[6];   // [32,1024]
  float* out = (float*)d_out;

  char* ws = (char*)d_ws;
  u16* qh    = (u16*)(ws);                      // 16 MB  [bh][n][64]
  u16* kh    = (u16*)(ws + 16777216);           // 16 MB  [bh][n][64]
  u16* xb    = (u16*)(ws + 33554432);           // 16 MB  (xb, then vT reuses)
  u16* vTg   = (u16*)(ws + 33554432);           // 16 MB  [bh][64][1024]
  u16* vtmp  = (u16*)(ws + 50331648);           // 16 MB  (vtmp, then ob reuses)
  u16* ob    = (u16*)(ws + 50331648);           // 16 MB  [n][512]
  u16* Wqkvt = (u16*)(ws + 67108864);           // 1.5 MB [1536][512]
  u16* Woutt = (u16*)(ws + 68681728);           // 0.5 MB [512][512]
  u16* ub    = (u16*)(ws + 69206016);           // 64 KB  [1024][32] (u*log2e)
  u16* vTb   = (u16*)(ws + 69271552);           // 64 KB  [1024][32]

  prep<<<5168, 256, 0, stream>>>(x, xb, u, ub, Wqkv, Wqkvt, Wout, Woutt, vlr, vTb);
  gemm128<0><<<dim3(12, 128), 256, 0, stream>>>(xb, Wqkvt, bqkv, qh, kh, vtmp, nullptr);
  vtrans<<<dim3(2, 32, 128), 256, 0, stream>>>(vtmp, vTg);
  attn32<<<dim3(8, 128), 256, 0, stream>>>(qh, kh, vTg, ub, vTb, ob);
  gemm128<1><<<dim3(4, 128), 256, 0, stream>>>(ob, Woutt, bout, nullptr, nullptr, nullptr, out);
}

// Round 6
// 207.379 us; speedup vs baseline: 1.7758x; 1.0633x over previous
//
#include <hip/hip_runtime.h>
#include <hip/hip_bf16.h>

typedef unsigned short u16;
typedef __attribute__((ext_vector_type(8))) short short8;
typedef __attribute__((ext_vector_type(4))) float f32x4;
typedef __attribute__((ext_vector_type(16))) float f32x16;
typedef __attribute__((ext_vector_type(4))) int i32x4;
typedef __attribute__((ext_vector_type(2))) int i32x2;

#define MFMA16(a,b,c) __builtin_amdgcn_mfma_f32_16x16x32_bf16((a),(b),(c),0,0,0)
#define MFMA32(a,b,c) __builtin_amdgcn_mfma_f32_32x32x16_bf16((a),(b),(c),0,0,0)

__device__ __forceinline__ u16 f2bf(float f) {
  union { float f; unsigned int u; } x; x.f = f;
  unsigned int u = x.u;
  return (u16)((u + 0x7fffu + ((u >> 16) & 1u)) >> 16);  // RNE
}

// v_cvt_pk_bf16_f32: dst = {hi: bf16(b), lo: bf16(a)}
__device__ __forceinline__ unsigned cvtpk(float a, float b) {
  unsigned r;
  asm("v_cvt_pk_bf16_f32 %0, %1, %2" : "=v"(r) : "v"(a), "v"(b));
  return r;
}

// v_exp_f32: 2^x
__device__ __forceinline__ float exp2v(float x) {
  float r;
  asm("v_exp_f32 %0, %1" : "=v"(r) : "v"(x));
  return r;
}

// async global->LDS, 16B per lane (dst = wave-uniform base + lane*16)
__device__ __forceinline__ void gld16(const void* g, void* l) {
  __builtin_amdgcn_global_load_lds(
      (const __attribute__((address_space(1))) void*)g,
      (__attribute__((address_space(3))) void*)l, 16, 0, 0);
}

// ---------------- fused preprocessing ----------------------------------------
// blocks [0,4096): x fp32 -> xb bf16            (8 elems/thread)
// blocks [4096,4112): u fp32 *log2e -> ub bf16
// blocks [4112,4880): Wqkv transpose -> Wqkvt [1536][512]
// blocks [4880,5136): Wout transpose -> Woutt [512][512]
// blocks [5136,5168): vlr  transpose -> vTb   [1024][32]
__global__ __launch_bounds__(256) void prep(
    const float* __restrict__ x, u16* __restrict__ xb,
    const float* __restrict__ u, u16* __restrict__ ub,
    const float* __restrict__ Wqkv, u16* __restrict__ Wqkvt,
    const float* __restrict__ Wout, u16* __restrict__ Woutt,
    const float* __restrict__ vlr, u16* __restrict__ vTb) {
  __shared__ float tile[32][33];
  int bid = blockIdx.x, tid = threadIdx.x;
  if (bid < 4112) {
    const float* in; u16* out; size_t i; float sc;
    if (bid < 4096) { in = x; out = xb; i = (size_t)bid * 256 + tid; sc = 1.f; }
    else { in = u; out = ub; i = (size_t)(bid - 4096) * 256 + tid; sc = 1.44269504f; }
    f32x4 a = *(const f32x4*)(in + i * 8);
    f32x4 b = *(const f32x4*)(in + i * 8 + 4);
    union { short8 s; u16 us[8]; } r;
    #pragma unroll
    for (int j = 0; j < 4; ++j) { r.us[j] = f2bf(a[j] * sc); r.us[4 + j] = f2bf(b[j] * sc); }
    *(short8*)&out[i * 8] = r.s;
    return;
  }
  int tb = bid - 4112;
  const float* in; u16* out; int rows, cols, bx, by;
  if (tb < 768)       { in = Wqkv; out = Wqkvt; rows = 512; cols = 1536; bx = tb % 48; by = tb / 48; }
  else if (tb < 1024) { int q = tb - 768; in = Wout; out = Woutt; rows = 512; cols = 512; bx = q % 16; by = q / 16; }
  else                { in = vlr; out = vTb; rows = 32; cols = 1024; bx = tb - 1024; by = 0; }
  int bc = bx * 32, br = by * 32;
  int tx = tid & 31, ty = tid >> 5;
  #pragma unroll
  for (int i = ty; i < 32; i += 8)
    tile[i][tx] = in[(size_t)(br + i) * cols + bc + tx];
  __syncthreads();
  #pragma unroll
  for (int i = ty; i < 32; i += 8)
    out[(size_t)(bc + i) * rows + br + tx] = f2bf(tile[tx][i]);
}

// ---------------- GEMM 128x128 tile, BK=64, 4 waves, global_load_lds ---------
// MODE 0: A=xb bf16 [16384,512], Bt=Wqkvt [1536,512]; epilogue: +bqkv,
//         q: (elu+1)*0.125*log2e -> qh[bh][n][64]; k: elu+1 -> kh;
//         v: written TRANSPOSED -> ov[bh][64 e][1024 n] (packed 8B stores)
// MODE 1: A=ob bf16 [16384,512], Bt=Woutt [512,512]; +bout -> fp32 out
template<int MODE>
__global__ __launch_bounds__(256) void gemm128(
    const u16* __restrict__ A, const u16* __restrict__ Bt,
    const float* __restrict__ bias,
    u16* __restrict__ oq, u16* __restrict__ ok, u16* __restrict__ ov,
    float* __restrict__ fo) {
  const int K = 512;
  __shared__ __align__(16) u16 As[128 * 64];
  __shared__ __align__(16) u16 Bs[128 * 64];
  int tid = threadIdx.x;
  int w = tid >> 6, ln = tid & 63, lo = ln & 15, hi = ln >> 4;
  int wr = (w >> 1) * 64, wc = (w & 1) * 64;
  // XCD-chunked bijective swizzle (gridDim.y % 8 == 0)
  int lin = blockIdx.y * gridDim.x + blockIdx.x;
  int xcd = lin & 7, idx = lin >> 3;
  int perx = gridDim.x, rows_per = gridDim.y >> 3;
  int by = xcd * rows_per + idx / perx;
  int bx = idx % perx;
  int bm = by * 128, bn = bx * 128;

  f32x4 acc[4][4];
  #pragma unroll
  for (int m = 0; m < 4; ++m)
    #pragma unroll
    for (int n = 0; n < 4; ++n)
      acc[m][n] = (f32x4){0.f, 0.f, 0.f, 0.f};

  for (int k0 = 0; k0 < K; k0 += 64) {
    #pragma unroll
    for (int i = 0; i < 4; ++i) {
      int c = i * 256 + w * 64 + ln;
      int r = c >> 3, cc = c & 7;
      gld16(&A[(size_t)(bm + r) * K + k0 + ((cc ^ (r & 7)) << 3)], &As[c << 3]);
    }
    #pragma unroll
    for (int i = 0; i < 4; ++i) {
      int c = i * 256 + w * 64 + ln;
      int r = c >> 3, cc = c & 7;
      gld16(&Bt[(size_t)(bn + r) * K + k0 + ((cc ^ (r & 7)) << 3)], &Bs[c << 3]);
    }
    __syncthreads();
    #pragma unroll
    for (int ks = 0; ks < 2; ++ks) {
      short8 a[4], b[4];
      #pragma unroll
      for (int m = 0; m < 4; ++m) {
        int row = wr + m * 16 + lo;
        a[m] = *(const short8*)&As[row * 64 + (((ks * 4 + hi) ^ (lo & 7)) << 3)];
      }
      #pragma unroll
      for (int n = 0; n < 4; ++n) {
        int row = wc + n * 16 + lo;
        b[n] = *(const short8*)&Bs[row * 64 + (((ks * 4 + hi) ^ (lo & 7)) << 3)];
      }
      #pragma unroll
      for (int m = 0; m < 4; ++m)
        #pragma unroll
        for (int n = 0; n < 4; ++n)
          acc[m][n] = MFMA16(a[m], b[n], acc[m][n]);
    }
    __syncthreads();
  }
  #pragma unroll
  for (int m = 0; m < 4; ++m)
    #pragma unroll
    for (int n = 0; n < 4; ++n) {
      int col = bn + wc + n * 16 + lo;
      int row0 = bm + wr + m * 16 + hi * 4;
      if (MODE == 0) {
        int type = col >> 9, hd = (col >> 6) & 7, e = col & 63;
        float bv = bias[col];
        if (type < 2) {
          u16* dst = (type == 0) ? oq : ok;
          #pragma unroll
          for (int r = 0; r < 4; ++r) {
            float v = acc[m][n][r] + bv;
            v = (v > 0.f) ? (v + 1.f) : __expf(v);
            if (type == 0) v *= 0.18033688f;   // 0.125 * log2(e)
            int row = row0 + r;
            dst[(size_t)(((row >> 10) << 3) + hd) * 65536 + (size_t)(row & 1023) * 64 + e] = f2bf(v);
          }
        } else {
          // V transposed: ov[bh][e][n]; 4 acc values are contiguous in n
          float v0 = acc[m][n][0] + bv, v1 = acc[m][n][1] + bv;
          float v2 = acc[m][n][2] + bv, v3 = acc[m][n][3] + bv;
          i32x2 d = {(int)cvtpk(v0, v1), (int)cvtpk(v2, v3)};
          int bidx = row0 >> 10;
          *(i32x2*)&ov[(size_t)((bidx << 3) + hd) * 65536 + (size_t)e * 1024 + (row0 & 1023)] = d;
        }
      } else {
        #pragma unroll
        for (int r = 0; r < 4; ++r)
          fo[(size_t)(row0 + r) * 512 + col] = acc[m][n][r] + bias[col];
      }
    }
}

// ---------------- flash attention: 4 waves x 64 q-cols, dbuf 2-phase ---------
// qh/kh [bh][1024][64] bf16 (q pre: (elu+1)/8*log2e); vt [bh][64][1024] (V^T)
// ub [1024][32] bf16 (u*log2e); vtb [1024][32] bf16 (v^T, direct global reads)
// Each wave owns 64 q (2 B-operand sets) so every A-frag (K/V) read feeds 2x MFMA.
__global__ __launch_bounds__(256, 2) void attn64q(
    const u16* __restrict__ qh, const u16* __restrict__ kh,
    const u16* __restrict__ vt, const u16* __restrict__ ub,
    const u16* __restrict__ vtb, u16* __restrict__ ob) {
  __shared__ __align__(16) u16 Ks[2][64 * 64];   // [m][d], chunk-swizzled
  __shared__ __align__(16) u16 Vs[2][64 * 64];   // [e][m], chunk-swizzled
  int tid = threadIdx.x;
  int w = tid >> 6, ln = tid & 63;
  int m32 = ln & 31, h = ln >> 5;
  // XCD swizzle: 16 contiguous bh per XCD (grid 512 = 8 XCD x 64)
  int lin = blockIdx.y * gridDim.x + blockIdx.x;
  int xcd = lin & 7, idx = lin >> 3;           // idx in [0,64)
  int bh = xcd * 16 + (idx >> 2);
  int q0 = (idx & 3) * 256 + w * 64;
  size_t bhb = (size_t)bh << 16;

  short8 qf[2][4], uf[2][2];
  #pragma unroll
  for (int s = 0; s < 2; ++s) {
    int qc = q0 + s * 32 + m32;
    #pragma unroll
    for (int ks = 0; ks < 4; ++ks)
      qf[s][ks] = *(const short8*)&qh[bhb + (size_t)qc * 64 + ks * 16 + h * 8];
    #pragma unroll
    for (int k2 = 0; k2 < 2; ++k2)
      uf[s][k2] = *(const short8*)&ub[(size_t)qc * 32 + k2 * 16 + h * 8];
  }

  auto STAGE = [&](int buf, int kv) {
    #pragma unroll
    for (int i = 0; i < 2; ++i) {
      int c = i * 256 + w * 64 + ln;
      int r = c >> 3, cc = c & 7;
      gld16(&kh[bhb + (size_t)(kv + r) * 64 + ((cc ^ (r & 7)) << 3)], &Ks[buf][c << 3]);
      gld16(&vt[bhb + (size_t)r * 1024 + kv + ((cc ^ (r & 7)) << 3)], &Vs[buf][c << 3]);
    }
  };

  f32x16 o[2][2];
  #pragma unroll
  for (int s = 0; s < 2; ++s)
    #pragma unroll
    for (int e = 0; e < 2; ++e)
      #pragma unroll
      for (int i = 0; i < 16; ++i) o[s][e][i] = 0.f;
  float mrun[2] = {-3e38f, -3e38f}, lrun[2] = {0.f, 0.f};

  int cur = 0;
  STAGE(0, 0);
  __syncthreads();

  for (int t = 0; t < 16; ++t) {
    int kv = t * 64;
    if (t < 15) STAGE(cur ^ 1, kv + 64);

    // low-rank bias A-frags: direct global (vtb is 64KB, L2-resident)
    short8 tf[2][2];
    #pragma unroll
    for (int k2 = 0; k2 < 2; ++k2) {
      tf[k2][0] = *(const short8*)&vtb[(size_t)(kv + m32) * 32 + k2 * 16 + h * 8];
      tf[k2][1] = *(const short8*)&vtb[(size_t)(kv + 32 + m32) * 32 + k2 * 16 + h * 8];
    }

    // ---- S'^T = vtb*ub + K*Q  (lane col = q; [set][kv-half])
    f32x16 sA[2][2];
    #pragma unroll
    for (int s = 0; s < 2; ++s)
      #pragma unroll
      for (int e = 0; e < 2; ++e)
        #pragma unroll
        for (int i = 0; i < 16; ++i) sA[s][e][i] = 0.f;

    __builtin_amdgcn_s_setprio(1);
    #pragma unroll
    for (int k2 = 0; k2 < 2; ++k2)
      #pragma unroll
      for (int s = 0; s < 2; ++s) {
        sA[s][0] = MFMA32(tf[k2][0], uf[s][k2], sA[s][0]);
        sA[s][1] = MFMA32(tf[k2][1], uf[s][k2], sA[s][1]);
      }
    #pragma unroll
    for (int ks = 0; ks < 4; ++ks) {
      short8 k0f = *(const short8*)&Ks[cur][m32 * 64 + (((ks * 2 + h) ^ (m32 & 7)) << 3)];
      short8 k1f = *(const short8*)&Ks[cur][(32 + m32) * 64 + (((ks * 2 + h) ^ (m32 & 7)) << 3)];
      #pragma unroll
      for (int s = 0; s < 2; ++s) {
        sA[s][0] = MFMA32(k0f, qf[s][ks], sA[s][0]);
        sA[s][1] = MFMA32(k1f, qf[s][ks], sA[s][1]);
      }
    }
    __builtin_amdgcn_s_setprio(0);

    // ---- online softmax per set (exp2 domain, defer-max THR=8*log2e)
    unsigned pk[2][2][4][2];
    #pragma unroll
    for (int s = 0; s < 2; ++s) {
      float pm = fmaxf(sA[s][0][0], sA[s][0][1]);
      #pragma unroll
      for (int i = 2; i < 16; i += 2) pm = fmaxf(fmaxf(pm, sA[s][0][i]), sA[s][0][i + 1]);
      #pragma unroll
      for (int i = 0; i < 16; i += 2) pm = fmaxf(fmaxf(pm, sA[s][1][i]), sA[s][1][i + 1]);
      pm = fmaxf(pm, __shfl_xor(pm, 32));
      if (!__all(pm - mrun[s] <= 11.5f)) {
        float nm = fmaxf(mrun[s], pm);
        float al = exp2v(mrun[s] - nm);
        #pragma unroll
        for (int i = 0; i < 16; ++i) { o[s][0][i] *= al; o[s][1][i] *= al; }
        lrun[s] *= al;
        mrun[s] = nm;
      }
      float ls = 0.f;
      #pragma unroll
      for (int i = 0; i < 16; ++i) { float p = exp2v(sA[s][0][i] - mrun[s]); sA[s][0][i] = p; ls += p; }
      #pragma unroll
      for (int i = 0; i < 16; ++i) { float p = exp2v(sA[s][1][i] - mrun[s]); sA[s][1][i] = p; ls += p; }
      lrun[s] += ls;
      #pragma unroll
      for (int hf = 0; hf < 2; ++hf)
        #pragma unroll
        for (int r8 = 0; r8 < 4; ++r8) {
          pk[s][hf][r8][0] = cvtpk(sA[s][hf][r8 * 4 + 0], sA[s][hf][r8 * 4 + 1]);
          pk[s][hf][r8][1] = cvtpk(sA[s][hf][r8 * 4 + 2], sA[s][hf][r8 * 4 + 3]);
        }
    }

    // ---- PV: each V A-frag pair feeds both q-sets
    #pragma unroll
    for (int ms = 0; ms < 4; ++ms) {
      int kvt = ms >> 1, msl = ms & 1;
      short8 v0 = *(const short8*)&Vs[cur][m32 * 64 + (((ms * 2 + h) ^ (m32 & 7)) << 3)];
      short8 v1 = *(const short8*)&Vs[cur][(32 + m32) * 64 + (((ms * 2 + h) ^ (m32 & 7)) << 3)];
      #pragma unroll
      for (int s = 0; s < 2; ++s) {
        unsigned a0 = pk[s][kvt][2 * msl][0], b0 = pk[s][kvt][2 * msl + 1][0];
        unsigned a1 = pk[s][kvt][2 * msl][1], b1 = pk[s][kvt][2 * msl + 1][1];
        asm("v_permlane32_swap_b32 %0, %1" : "+v"(a0), "+v"(b0));
        asm("v_permlane32_swap_b32 %0, %1" : "+v"(a1), "+v"(b1));
        union { i32x4 i; short8 s8; } pu;
        pu.i = (i32x4){(int)a0, (int)a1, (int)b0, (int)b1};
        __builtin_amdgcn_s_setprio(1);
        o[s][0] = MFMA32(v0, pu.s8, o[s][0]);
        o[s][1] = MFMA32(v1, pu.s8, o[s][1]);
        __builtin_amdgcn_s_setprio(0);
      }
    }
    __syncthreads();   // drains prefetch vmcnt + all ds reads of buf[cur]
    cur ^= 1;
  }

  // ---- finalize: per set, lane col q = q0+s*32+m32; e rows in o regs
  int b = bh >> 3, hd = bh & 7;
  #pragma unroll
  for (int s = 0; s < 2; ++s) {
    float lt = lrun[s] + __shfl_xor(lrun[s], 32);
    float li = 1.f / lt;
    size_t orow = ((size_t)(b * 1024 + q0 + s * 32 + m32)) * 512 + hd * 64;
    #pragma unroll
    for (int et = 0; et < 2; ++et)
      #pragma unroll
      for (int r8 = 0; r8 < 4; ++r8) {
        float v0 = o[s][et][r8 * 4 + 0] * li;
        float v1 = o[s][et][r8 * 4 + 1] * li;
        float v2 = o[s][et][r8 * 4 + 2] * li;
        float v3 = o[s][et][r8 * 4 + 3] * li;
        i32x2 d = {(int)cvtpk(v0, v1), (int)cvtpk(v2, v3)};
        *(i32x2*)&ob[orow + et * 32 + 8 * r8 + 4 * h] = d;
      }
  }
}

extern "C" void kernel_launch(void* const* d_in, const int* in_sizes, int n_in,
                              void* d_out, int out_size, void* d_ws, size_t ws_size,
                              hipStream_t stream) {
  const float* x    = (const float*)d_in[0];   // [16384,512]
  const float* Wqkv = (const float*)d_in[1];   // [512,1536]
  const float* bqkv = (const float*)d_in[2];   // [1536]
  const float* Wout = (const float*)d_in[3];   // [512,512]
  const float* bout = (const float*)d_in[4];   // [512]
  const float* u    = (const float*)d_in[5];   // [1024,32]
  const float* vlr  = (const float*)d_in[6];   // [32,1024]
  float* out = (float*)d_out;

  char* ws = (char*)d_ws;
  u16* qh    = (u16*)(ws);                      // 16 MB  [bh][n][64]
  u16* kh    = (u16*)(ws + 16777216);           // 16 MB  [bh][n][64]
  u16* xb    = (u16*)(ws + 33554432);           // 16 MB  (gemm0 input)
  u16* ob    = (u16*)(ws + 33554432);           // 16 MB  (attn out, reuses xb)
  u16* vTg   = (u16*)(ws + 50331648);           // 16 MB  [bh][64][1024]
  u16* Wqkvt = (u16*)(ws + 67108864);           // 1.5 MB [1536][512]
  u16* Woutt = (u16*)(ws + 68681728);           // 0.5 MB [512][512]
  u16* ub    = (u16*)(ws + 69206016);           // 64 KB  [1024][32] (u*log2e)
  u16* vTb   = (u16*)(ws + 69271552);           // 64 KB  [1024][32]

  prep<<<5168, 256, 0, stream>>>(x, xb, u, ub, Wqkv, Wqkvt, Wout, Woutt, vlr, vTb);
  gemm128<0><<<dim3(12, 128), 256, 0, stream>>>(xb, Wqkvt, bqkv, qh, kh, vTg, nullptr);
  attn64q<<<dim3(4, 128), 256, 0, stream>>>(qh, kh, vTg, ub, vTb, ob);
  gemm128<1><<<dim3(4, 128), 256, 0, stream>>>(ob, Woutt, bout, nullptr, nullptr, nullptr, out);
}